// Round 19
// baseline (1690.291 us; speedup 1.0000x reference)
//
#include <hip/hip_runtime.h>
#include <hip/hip_bf16.h>
#include <cstdint>
#include <cstddef>

typedef __bf16 bf16;
typedef __attribute__((ext_vector_type(8))) __bf16 bf16x8;
typedef __attribute__((ext_vector_type(4))) __bf16 bf16x4;
typedef __attribute__((ext_vector_type(4))) float f32x4;

__device__ __forceinline__ f32x4 mfma16(bf16x8 a, bf16x8 b, f32x4 c) {
    return __builtin_amdgcn_mfma_f32_16x16x32_bf16(a, b, c, 0, 0, 0);
}

__device__ __forceinline__ void async_copy16(const void* g, void* l) {
    __builtin_amdgcn_global_load_lds((const __attribute__((address_space(1))) void*)g,
                                     (__attribute__((address_space(3))) void*)l,
                                     16, 0, 0);
}

template<int Ncnt> __device__ __forceinline__ void waitv();
template<> __device__ __forceinline__ void waitv<0>() { asm volatile("s_waitcnt vmcnt(0)" ::: "memory"); }
template<> __device__ __forceinline__ void waitv<2>() { asm volatile("s_waitcnt vmcnt(2)" ::: "memory"); }
template<> __device__ __forceinline__ void waitv<3>() { asm volatile("s_waitcnt vmcnt(3)" ::: "memory"); }
template<> __device__ __forceinline__ void waitv<4>() { asm volatile("s_waitcnt vmcnt(4)" ::: "memory"); }

__device__ __forceinline__ void wait_g(int n) {
    if (n == 2) waitv<2>();
    else if (n == 3) waitv<3>();
    else waitv<4>();
}

// ---------------- device bodies ----------------
__device__ __forceinline__ void ln_vec(f32x4 v, const float* __restrict__ sc,
                                       const float* __restrict__ bi, bf16* __restrict__ out,
                                       int row, int t, float* red)
{
    float s = v[0] + v[1] + v[2] + v[3];
    float q = v[0]*v[0] + v[1]*v[1] + v[2]*v[2] + v[3]*v[3];
    #pragma unroll
    for (int o = 1; o < 64; o <<= 1) { s += __shfl_xor(s, o); q += __shfl_xor(q, o); }
    const int wv = t >> 6, lane = t & 63;
    if (lane == 0) { red[wv] = s; red[4 + wv] = q; }
    __syncthreads();
    s = red[0] + red[1] + red[2] + red[3];
    q = red[4] + red[5] + red[6] + red[7];
    const float mean = s * (1.f / 1024.f);
    const float var  = q * (1.f / 1024.f) - mean * mean;
    const float rstd = rsqrtf(var + 1e-5f);
    const f32x4 scv = ((const f32x4*)sc)[t];
    const f32x4 biv = ((const f32x4*)bi)[t];
    bf16x4 o4;
    #pragma unroll
    for (int j = 0; j < 4; j++) o4[j] = (bf16)((v[j] - mean) * rstd * scv[j] + biv[j]);
    *(bf16x4*)(out + (size_t)row * 1024 + t * 4) = o4;
}

__device__ __forceinline__ void ln_body(const float* __restrict__ x, const float* __restrict__ sc,
                                        const float* __restrict__ bi, bf16* __restrict__ out,
                                        int row, int t, float* red)
{
    const f32x4 v = ((const f32x4*)(x + (size_t)row * 1024))[t];
    ln_vec(v, sc, bi, out, row, t, red);
}

__device__ __forceinline__ void wcvt_body(const float* __restrict__ W, bf16* __restrict__ BT,
                                          int K, int N, int bid, int tidx, float (*tile)[65])
{
    const int nx = N >> 6;
    const int n0 = (bid % nx) << 6, k0 = (bid / nx) << 6;
    const int tx = tidx & 15, ty = tidx >> 4;
    #pragma unroll
    for (int r = 0; r < 4; r++) {
        const f32x4 v = *(const f32x4*)&W[(size_t)(k0 + ty + r*16) * N + n0 + tx*4];
        tile[ty + r*16][tx*4 + 0] = v[0];
        tile[ty + r*16][tx*4 + 1] = v[1];
        tile[ty + r*16][tx*4 + 2] = v[2];
        tile[ty + r*16][tx*4 + 3] = v[3];
    }
    __syncthreads();
    #pragma unroll
    for (int r = 0; r < 4; r++) {
        const int n = ty + r*16;
        bf16x4 o;
        #pragma unroll
        for (int j = 0; j < 4; j++) o[j] = (bf16)tile[tx*4 + j][n];
        *(bf16x4*)&BT[(size_t)(n0 + n) * K + k0 + tx*4] = o;
    }
}

// ---------------- slim front: embed+ln1(l0) + wcvt qkv(l0) only ----------------
__global__ __launch_bounds__(256)
void front_kernel(const int* __restrict__ ids, const float* __restrict__ te,
                  const float* __restrict__ pe, float* __restrict__ x,
                  const float* __restrict__ sc, const float* __restrict__ bi,
                  bf16* __restrict__ out,
                  const float* __restrict__ qkvw0, bf16* __restrict__ wTq)
{
    __shared__ float tile[64][65];
    __shared__ float red[8];
    const int bid = blockIdx.x, t = threadIdx.x;
    if (bid < 2048) {
        const int s = bid & 1023;
        const int id = ids[bid];
        const f32x4 a = ((const f32x4*)(te + (size_t)id * 1024))[t];
        const f32x4 b = ((const f32x4*)(pe + (size_t)s * 1024))[t];
        const f32x4 v = a + b;
        ((f32x4*)(x + (size_t)bid * 1024))[t] = v;
        ln_vec(v, sc, bi, out, bid, t, red);
    } else {
        wcvt_body(qkvw0, wTq, 1024, 3072, bid - 2048, t, tile);
    }
}

// ---------------- LN dispatch (ln2), also zeroes this layer's completion counters -------
__global__ __launch_bounds__(256)
void ln_kernel(const float* __restrict__ x, const float* __restrict__ sc,
               const float* __restrict__ bi, bf16* __restrict__ out,
               int* __restrict__ cnt_zero)
{
    __shared__ float red[8];
    if (blockIdx.x == 0 && threadIdx.x < 16) cnt_zero[threadIdx.x] = 0;
    ln_body(x, sc, bi, out, blockIdx.x, threadIdx.x, red);
}

// ---------------- fused attention + ALL off-critical-path weight converts ----------------
__global__ __launch_bounds__(256)
void attn_wcvt_kernel(const bf16* __restrict__ qkv, const bf16* __restrict__ vT,
                      bf16* __restrict__ attno,
                      const float* __restrict__ qkvw_n, bf16* __restrict__ wTq_n, int nbq,
                      const float* __restrict__ w1, bf16* __restrict__ wT1,
                      const float* __restrict__ w2, bf16* __restrict__ wT2,
                      const float* __restrict__ outw, bf16* __restrict__ wTo,
                      const float* __restrict__ lmw, bf16* __restrict__ wTlm, int lm_lo)
{
    __shared__ __align__(16) char smem[49664];
    const int bid = blockIdx.x, tid = threadIdx.x;

    if (bid >= 512) {
        float (*tile)[65] = (float(*)[65])smem;
        int wb = bid - 512;
        if (wb < nbq) { wcvt_body(qkvw_n, wTq_n, 1024, 3072, wb, tid, tile); return; }
        wb -= nbq;
        if (wb < 1024) { wcvt_body(w1, wT1, 1024, 4096, wb, tid, tile); return; }
        wb -= 1024;
        if (wb < 1024) { wcvt_body(w2, wT2, 4096, 1024, wb, tid, tile); return; }
        wb -= 1024;
        if (wb < 256)  { wcvt_body(outw, wTo, 1024, 1024, wb, tid, tile); return; }
        wb -= 256;
        wcvt_body(lmw, wTlm, 1024, 32000, lm_lo + wb, tid, tile);
        return;
    }

    bf16* Ksh = (bf16*)smem;
    bf16* Vt  = (bf16*)(smem + 16384);
    bf16* Plds = (bf16*)(smem + 32768);
#define PLDS(w_, r_, c_) Plds[(((w_) << 4) + (r_)) * 132 + (c_)]

    const int b = (bid & 31) >> 4, h = bid & 15;
    const int qb = bid >> 5;
    const int lane = tid & 63, wave = tid >> 6;
    const bf16* base = qkv + (size_t)b * 1024 * 3072;
    const bf16* vbase = vT + (size_t)(b*16 + h) * 64 * 1024;
    const int qrow0 = qb * 64 + wave * 16;
    const int l15 = lane & 15;

    bf16x8 aQ[2];
    {
        const int qr = qrow0 + l15;
        const bf16* qp = base + (size_t)qr * 3072 + h * 64 + ((lane >> 4) << 3);
        aQ[0] = *(const bf16x8*)qp;
        aQ[1] = *(const bf16x8*)(qp + 32);
    }
    float m_i[4] = {-1e30f, -1e30f, -1e30f, -1e30f};
    float l_i[4] = {0.f, 0.f, 0.f, 0.f};
    f32x4 acc[4];
    #pragma unroll
    for (int nb = 0; nb < 4; nb++) acc[nb] = f32x4{0.f, 0.f, 0.f, 0.f};

    const int swzA = (((lane >> 4)     ^ (lane & 7)) << 3);
    const int swzB = (((4 + (lane >> 4)) ^ (lane & 7)) << 3);

    for (int ck = 0; ck < 8; ck++) {
        __syncthreads();
        #pragma unroll
        for (int p = 0; p < 4; p++) {
            const int c = p * 256 + tid;
            const int rw = c >> 3;
            const int kc = (c & 7) ^ (rw & 7);
            async_copy16(base + (size_t)(ck*128 + rw) * 3072 + 1024 + h*64 + kc*8, &Ksh[c * 8]);
        }
        #pragma unroll
        for (int p = 0; p < 4; p++) {
            const int c = p * 256 + tid;
            const int rw = c >> 4;
            const int kc = (c & 15) ^ (rw & 7);
            async_copy16(vbase + (size_t)rw * 1024 + ck*128 + kc*8, &Vt[c * 8]);
        }
        waitv<4>();
        __builtin_amdgcn_sched_barrier(0);
        __builtin_amdgcn_s_barrier();

        f32x4 sc[8];
        #pragma unroll
        for (int kk = 0; kk < 4; kk++) {
            const int kr0 = (kk*32 + l15) * 64;
            const int kr1 = kr0 + 16*64;
            f32x4 z{0.f, 0.f, 0.f, 0.f};
            z = mfma16(aQ[0], *(const bf16x8*)&Ksh[kr0 + swzA], z);
            z = mfma16(aQ[1], *(const bf16x8*)&Ksh[kr0 + swzB], z);
            sc[2*kk] = z;
            f32x4 z2{0.f, 0.f, 0.f, 0.f};
            z2 = mfma16(aQ[0], *(const bf16x8*)&Ksh[kr1 + swzA], z2);
            z2 = mfma16(aQ[1], *(const bf16x8*)&Ksh[kr1 + swzB], z2);
            sc[2*kk+1] = z2;
        }

        float c[4];
        #pragma unroll
        for (int i = 0; i < 4; i++) {
            float t = sc[0][i];
            #pragma unroll
            for (int e = 1; e < 8; e++) t = fmaxf(t, sc[e][i]);
            #pragma unroll
            for (int o = 1; o < 16; o <<= 1) t = fmaxf(t, __shfl_xor(t, o));
            t *= 0.125f;
            const float mnew = fmaxf(m_i[i], t);
            c[i] = __expf(m_i[i] - mnew);
            float p[8];
            float rs = 0.f;
            #pragma unroll
            for (int e = 0; e < 8; e++) {
                p[e] = __expf(fmaf(sc[e][i], 0.125f, -mnew));
                rs += p[e];
            }
            #pragma unroll
            for (int o = 1; o < 16; o <<= 1) rs += __shfl_xor(rs, o);
            l_i[i] = l_i[i] * c[i] + rs;
            m_i[i] = mnew;
            const int pr = ((lane >> 4) << 2) + i;
            #pragma unroll
            for (int e = 0; e < 8; e++)
                PLDS(wave, pr, (e >> 1) * 32 + (e & 1) * 16 + l15) = (bf16)p[e];
        }

        waitv<0>();
        __builtin_amdgcn_sched_barrier(0);
        __builtin_amdgcn_s_barrier();

        #pragma unroll
        for (int nb = 0; nb < 4; nb++) {
            f32x4 a = acc[nb];
            a[0] *= c[0]; a[1] *= c[1]; a[2] *= c[2]; a[3] *= c[3];
            acc[nb] = a;
        }
        #pragma unroll
        for (int kk = 0; kk < 4; kk++) {
            const bf16x8 aP = *(const bf16x8*)&PLDS(wave, l15, kk*32 + ((lane >> 4) << 3));
            #pragma unroll
            for (int nb = 0; nb < 4; nb++) {
                const int r = nb*16 + l15;
                const int chk = (kk*4 + (lane >> 4)) ^ (r & 7);
                const bf16x8 bV = *(const bf16x8*)&Vt[r*128 + chk*8];
                acc[nb] = mfma16(aP, bV, acc[nb]);
            }
        }
    }
    #pragma unroll
    for (int nb = 0; nb < 4; nb++) {
        #pragma unroll
        for (int i = 0; i < 4; i++) {
            const int row = qrow0 + ((lane >> 4) << 2) + i;
            const float o = acc[nb][i] / l_i[i];
            attno[(size_t)(b*1024 + row) * 1024 + h*64 + nb*16 + l15] = (bf16)o;
        }
    }
#undef PLDS
}

// ---------------- 8-phase GEMM (T3+T4), generalized BN ----------------
template<int BM, int BN, int EPI, int KSPLIT>
__global__ __launch_bounds__(512, 2)
void gemm256_kernel(const bf16* __restrict__ A, const bf16* __restrict__ BT,
                    const float* __restrict__ bias, float* __restrict__ resid,
                    bf16* __restrict__ outb, float* __restrict__ outf,
                    bf16* __restrict__ vt, int N, int K)
{
    constexpr int MT = 2048 / BM;
    constexpr int FM = BM / 32;
    constexpr int FN = BN / 64;
    constexpr int HM = FM / 2;
    constexpr int ACH = BM * 4;
    constexpr int BCH = BN * 4;
    constexpr int LA = (ACH + 511) >> 9;
    constexpr int LB = (BCH + 511) >> 9;
    constexpr int ASUB = BM * 32;
    constexpr int BSUB = BN * 32;
    extern __shared__ __align__(16) char smem_raw[];
    bf16* smem = (bf16*)smem_raw;

    const int nwg = gridDim.x;
    const int q = nwg >> 3, rr = nwg & 7;
    const int xcd = blockIdx.x & 7, ix = blockIdx.x >> 3;
    const int nid = (xcd < rr ? xcd * (q + 1) : rr * (q + 1) + (xcd - rr) * q) + ix;
    const int tiles = nwg / KSPLIT;
    const int ks = nid / tiles;
    const int tile = nid % tiles;
    const int bm = tile % MT, bn = tile / MT;

    const int tid = threadIdx.x, lane = tid & 63, wave = tid >> 6;
    const int wr = wave >> 2, wc = wave & 3;

    const int myB = ((BCH & 511) == 0) ? (BCH >> 9)
                    : ((tid < (BCH & 511)) ? (BCH >> 9) + 1 : (BCH >> 9));
    const int wcount = LA + myB;

    f32x4 acc[FM][FN];
    #pragma unroll
    for (int m = 0; m < FM; m++)
        #pragma unroll
        for (int n = 0; n < FN; n++) acc[m][n] = f32x4{0.f, 0.f, 0.f, 0.f};

    const bf16* Abase = A  + (size_t)bm * BM * K;
    const bf16* Bbase = BT + (size_t)bn * BN * K;
    const int Ts = (K >> 6) / KSPLIT;
    const int t0 = ks * Ts;

    const int l15 = lane & 15;
    const int swz = (((lane >> 4) ^ ((l15 >> 1) & 3)) << 3);
    const int arow0 = wr * (BM / 2) + l15;
    const int brow0 = wc * (BN / 4) + l15;

#define ABASE_(p_, ks_) (((p_)*2 + (ks_)) * ASUB)
#define BBASE_(p_, ks_) (4*ASUB + ((p_)*2 + (ks_)) * BSUB)
#define STAGE_A(p_, kt_, ks_) { _Pragma("unroll") for (int i = 0; i < LA; i++) { \
    const int c = tid + i * 512; \
    if ((ACH & 511) == 0 || c < ACH) { \
      const int rw = c >> 2; \
      const int kc = (c & 3) ^ ((rw >> 1) & 3); \
      async_copy16(Abase + (size_t)rw * K + (kt_)*64 + (ks_)*32 + kc*8, \
                   &smem[ABASE_(p_, ks_) + c*8]); } } }
#define STAGE_B(p_, kt_, ks_) { _Pragma("unroll") for (int i = 0; i < LB; i++) { \
    const int c = tid + i * 512; \
    if ((BCH & 511) == 0 || c < BCH) { \
      const int rw = c >> 2; \
      const int kc = (c & 3) ^ ((rw >> 1) & 3); \
      async_copy16(Bbase + (size_t)rw * K + (kt_)*64 + (ks_)*32 + kc*8, \
                   &smem[BBASE_(p_, ks_) + c*8]); } } }
#define LOAD_B(p_, ks_) { _Pragma("unroll") for (int n = 0; n < FN; n++) \
    bfv[n] = *(const bf16x8*)&smem[BBASE_(p_, ks_) + (brow0 + n*16)*32 + swz]; }
#define LOAD_A(p_, ks_, mg) { _Pragma("unroll") for (int m = 0; m < HM; m++) \
    af[m] = *(const bf16x8*)&smem[ABASE_(p_, ks_) + (arow0 + ((mg)*HM + m)*16)*32 + swz]; }
#define QUAD(mg) { __builtin_amdgcn_s_setprio(1); \
    _Pragma("unroll") for (int m = 0; m < HM; m++) \
      _Pragma("unroll") for (int n = 0; n < FN; n++) \
        acc[(mg)*HM + m][n] = mfma16(af[m], bfv[n], acc[(mg)*HM + m][n]); \
    __builtin_amdgcn_s_setprio(0); }

    STAGE_A(0, t0, 0); STAGE_B(0, t0, 0); STAGE_A(0, t0, 1); STAGE_B(0, t0, 1);
    wait_g(wcount);
    __builtin_amdgcn_s_barrier();

    for (int tl = 0; tl < Ts; tl++) {
        const int b = tl & 1;
        const int kt1 = t0 + tl + 1;
        const bool more = (tl + 1) < Ts;
        bf16x8 af[HM], bfv[FN];
        LOAD_B(b, 0); LOAD_A(b, 0, 0);
        if (more) STAGE_A(b ^ 1, kt1, 0);
        __builtin_amdgcn_s_barrier();
        QUAD(0);
        __builtin_amdgcn_s_barrier();
        LOAD_A(b, 0, 1);
        if (more) STAGE_B(b ^ 1, kt1, 0);
        __builtin_amdgcn_s_barrier();
        QUAD(1);
        if (more) wait_g(wcount); else waitv<0>();
        __builtin_amdgcn_s_barrier();
        LOAD_B(b, 1); LOAD_A(b, 1, 0);
        if (more) STAGE_A(b ^ 1, kt1, 1);
        __builtin_amdgcn_s_barrier();
        QUAD(0);
        __builtin_amdgcn_s_barrier();
        LOAD_A(b, 1, 1);
        if (more) STAGE_B(b ^ 1, kt1, 1);
        __builtin_amdgcn_s_barrier();
        QUAD(1);
        if (more) wait_g(wcount);
        __builtin_amdgcn_s_barrier();
    }

    const int er = bm * BM + wr * (BM / 2) + ((lane >> 4) << 2);
    const int ec = bn * BN + wc * (BN / 4) + l15;
    #pragma unroll
    for (int n = 0; n < FN; n++) {
        const int col = ec + n * 16;
        const float bv = (EPI == 3) ? 0.f : ((KSPLIT > 1 && ks != 0) ? 0.f : bias[col]);
        #pragma unroll
        for (int m = 0; m < FM; m++) {
            const int row0 = er + m * 16;
            if constexpr (EPI == 4) {
                if (col < 2048) {
                    #pragma unroll
                    for (int i = 0; i < 4; i++)
                        outb[(size_t)(row0 + i) * N + col] = (bf16)(acc[m][n][i] + bv);
                } else {
                    bf16x4 o4;
                    #pragma unroll
                    for (int i = 0; i < 4; i++) o4[i] = (bf16)(acc[m][n][i] + bv);
                    const int b_ = row0 >> 10, tok = row0 & 1023;
                    *(bf16x4*)&vt[((size_t)(b_ * 1024 + (col - 2048))) * 1024 + tok] = o4;
                }
            } else {
                #pragma unroll
                for (int i = 0; i < 4; i++) {
                    const float v = acc[m][n][i] + bv;
                    const size_t off = (size_t)(row0 + i) * N + col;
                    if constexpr (EPI == 0) outb[off] = (bf16)v;
                    else if constexpr (EPI == 1) {
                        if constexpr (KSPLIT > 1) atomicAdd(&resid[off], v);
                        else resid[off] += v;
                    }
                    else if constexpr (EPI == 2) {
                        outb[off] = (bf16)(0.5f * v * (1.f + erff(v * 0.70710678118f)));
                    } else {
                        outf[off] = v;
                    }
                }
            }
        }
    }
#undef ABASE_
#undef BBASE_
#undef STAGE_A
#undef STAGE_B
#undef LOAD_A
#undef LOAD_B
#undef QUAD
}

// ---------------- mlp2 + fused LN of the updated residual (ln1[l+1] or lnf) --------------
// BM=128,BN=256,KSPLIT=4 fixed; N=1024,K=4096. 256 blocks @ 96KB LDS = 1 block/CU -> all
// co-resident; per-bm arrival counter (16 blocks: 4 bn x 4 ks); spin AFTER own work only.
__global__ __launch_bounds__(512, 2)
void gemm_mlp2ln_kernel(const bf16* __restrict__ A, const bf16* __restrict__ BT,
                        const float* __restrict__ bias, float* __restrict__ resid,
                        int* __restrict__ cnt,
                        const float* __restrict__ lnS, const float* __restrict__ lnB,
                        bf16* __restrict__ hout, int N, int K)
{
    constexpr int BM = 128, BN = 256, KSPLIT = 4;
    constexpr int MT = 16, FM = 4, FN = 4, HM = 2, LA = 1, LB = 2;
    constexpr int ASUB = BM * 32, BSUB = BN * 32;
    extern __shared__ __align__(16) char smem_raw[];
    bf16* smem = (bf16*)smem_raw;

    const int nwg = gridDim.x;
    const int q = nwg >> 3, rr = nwg & 7;
    const int xcd = blockIdx.x & 7, ix = blockIdx.x >> 3;
    const int nid = (xcd < rr ? xcd * (q + 1) : rr * (q + 1) + (xcd - rr) * q) + ix;
    const int tiles = nwg / KSPLIT;
    const int ks = nid / tiles;
    const int tile = nid % tiles;
    const int bm = tile % MT, bn = tile / MT;

    const int tid = threadIdx.x, lane = tid & 63, wave = tid >> 6;
    const int wr = wave >> 2, wc = wave & 3;

    f32x4 acc[FM][FN];
    #pragma unroll
    for (int m = 0; m < FM; m++)
        #pragma unroll
        for (int n = 0; n < FN; n++) acc[m][n] = f32x4{0.f, 0.f, 0.f, 0.f};

    const bf16* Abase = A  + (size_t)bm * BM * K;
    const bf16* Bbase = BT + (size_t)bn * BN * K;
    const int Ts = (K >> 6) / KSPLIT;
    const int t0 = ks * Ts;

    const int l15 = lane & 15;
    const int swz = (((lane >> 4) ^ ((l15 >> 1) & 3)) << 3);
    const int arow0 = wr * (BM / 2) + l15;
    const int brow0 = wc * (BN / 4) + l15;

#define ABASE_(p_, ks_) (((p_)*2 + (ks_)) * ASUB)
#define BBASE_(p_, ks_) (4*ASUB + ((p_)*2 + (ks_)) * BSUB)
#define STAGE_A(p_, kt_, ks_) { \
    const int c = tid; const int rw = c >> 2; \
    const int kc = (c & 3) ^ ((rw >> 1) & 3); \
    async_copy16(Abase + (size_t)rw * K + (kt_)*64 + (ks_)*32 + kc*8, \
                 &smem[ABASE_(p_, ks_) + c*8]); }
#define STAGE_B(p_, kt_, ks_) { _Pragma("unroll") for (int i = 0; i < LB; i++) { \
    const int c = tid + i * 512; const int rw = c >> 2; \
    const int kc = (c & 3) ^ ((rw >> 1) & 3); \
    async_copy16(Bbase + (size_t)rw * K + (kt_)*64 + (ks_)*32 + kc*8, \
                 &smem[BBASE_(p_, ks_) + c*8]); } }
#define LOAD_B(p_, ks_) { _Pragma("unroll") for (int n = 0; n < FN; n++) \
    bfv[n] = *(const bf16x8*)&smem[BBASE_(p_, ks_) + (brow0 + n*16)*32 + swz]; }
#define LOAD_A(p_, ks_, mg) { _Pragma("unroll") for (int m = 0; m < HM; m++) \
    af[m] = *(const bf16x8*)&smem[ABASE_(p_, ks_) + (arow0 + ((mg)*HM + m)*16)*32 + swz]; }
#define QUAD(mg) { __builtin_amdgcn_s_setprio(1); \
    _Pragma("unroll") for (int m = 0; m < HM; m++) \
      _Pragma("unroll") for (int n = 0; n < FN; n++) \
        acc[(mg)*HM + m][n] = mfma16(af[m], bfv[n], acc[(mg)*HM + m][n]); \
    __builtin_amdgcn_s_setprio(0); }

    STAGE_A(0, t0, 0); STAGE_B(0, t0, 0); STAGE_A(0, t0, 1); STAGE_B(0, t0, 1);
    waitv<3>();
    __builtin_amdgcn_s_barrier();

    for (int tl = 0; tl < Ts; tl++) {
        const int b = tl & 1;
        const int kt1 = t0 + tl + 1;
        const bool more = (tl + 1) < Ts;
        bf16x8 af[HM], bfv[FN];
        LOAD_B(b, 0); LOAD_A(b, 0, 0);
        if (more) STAGE_A(b ^ 1, kt1, 0);
        __builtin_amdgcn_s_barrier();
        QUAD(0);
        __builtin_amdgcn_s_barrier();
        LOAD_A(b, 0, 1);
        if (more) STAGE_B(b ^ 1, kt1, 0);
        __builtin_amdgcn_s_barrier();
        QUAD(1);
        if (more) waitv<3>(); else waitv<0>();
        __builtin_amdgcn_s_barrier();
        LOAD_B(b, 1); LOAD_A(b, 1, 0);
        if (more) STAGE_A(b ^ 1, kt1, 1);
        __builtin_amdgcn_s_barrier();
        QUAD(0);
        __builtin_amdgcn_s_barrier();
        LOAD_A(b, 1, 1);
        if (more) STAGE_B(b ^ 1, kt1, 1);
        __builtin_amdgcn_s_barrier();
        QUAD(1);
        if (more) waitv<3>();
        __builtin_amdgcn_s_barrier();
    }

    const int er = bm * BM + wr * 64 + ((lane >> 4) << 2);
    const int ec = bn * BN + wc * 64 + l15;
    #pragma unroll
    for (int n = 0; n < FN; n++) {
        const int col = ec + n * 16;
        const float bv = (ks != 0) ? 0.f : bias[col];
        #pragma unroll
        for (int m = 0; m < FM; m++) {
            #pragma unroll
            for (int i = 0; i < 4; i++) {
                const float v = acc[m][n][i] + bv;
                atomicAdd(&resid[(size_t)(er + m * 16 + i) * N + col], v);
            }
        }
    }

    // ---- completion counter + fused LN of rows bm*128..+128 spread over 16 blocks ----
    __threadfence();                      // release: drain + make atomics visible
    __syncthreads();
    if (tid == 0) {
        atomicAdd(cnt + bm, 1);
        while (__hip_atomic_load(cnt + bm, __ATOMIC_ACQUIRE, __HIP_MEMORY_SCOPE_AGENT) < 16)
            __builtin_amdgcn_s_sleep(8);
    }
    __syncthreads();
    __threadfence();                      // acquire: invalidate caches before reading x
    {
        float* red = (float*)smem_raw;    // 16 floats, LDS reuse
        const int rank = ks * 4 + bn;     // 0..15
        const int sub = tid >> 8, tt = tid & 255;
        const int wv8 = tid >> 6;
        #pragma unroll
        for (int it = 0; it < 4; it++) {
            const int row = bm * 128 + rank * 8 + it * 2 + sub;
            const f32x4 v = ((const f32x4*)(resid + (size_t)row * 1024))[tt];
            float s = v[0] + v[1] + v[2] + v[3];
            float qq = v[0]*v[0] + v[1]*v[1] + v[2]*v[2] + v[3]*v[3];
            #pragma unroll
            for (int o = 1; o < 64; o <<= 1) { s += __shfl_xor(s, o); qq += __shfl_xor(qq, o); }
            if ((tid & 63) == 0) { red[wv8] = s; red[8 + wv8] = qq; }
            __syncthreads();
            s  = red[sub*4+0] + red[sub*4+1] + red[sub*4+2] + red[sub*4+3];
            qq = red[8+sub*4+0] + red[8+sub*4+1] + red[8+sub*4+2] + red[8+sub*4+3];
            const float mean = s * (1.f / 1024.f);
            const float var  = qq * (1.f / 1024.f) - mean * mean;
            const float rstd = rsqrtf(var + 1e-5f);
            const f32x4 scv = ((const f32x4*)lnS)[tt];
            const f32x4 biv = ((const f32x4*)lnB)[tt];
            bf16x4 o4;
            #pragma unroll
            for (int j = 0; j < 4; j++) o4[j] = (bf16)((v[j] - mean) * rstd * scv[j] + biv[j]);
            *(bf16x4*)(hout + (size_t)row * 1024 + tt * 4) = o4;
            __syncthreads();
        }
    }
#undef ABASE_
#undef BBASE_
#undef STAGE_A
#undef STAGE_B
#undef LOAD_A
#undef LOAD_B
#undef QUAD
}

// ---------------- orchestration ----------------
extern "C" void kernel_launch(void* const* d_in, const int* in_sizes, int n_in,
                              void* d_out, int out_size, void* d_ws, size_t ws_size,
                              hipStream_t stream)
{
    const int*   ids     = (const int*)  d_in[0];
    const float* tok_emb = (const float*)d_in[1];
    const float* pos_emb = (const float*)d_in[2];
    const float* ln1_s   = (const float*)d_in[3];
    const float* ln1_b   = (const float*)d_in[4];
    const float* qkv_w   = (const float*)d_in[5];
    const float* qkv_b   = (const float*)d_in[6];
    const float* out_w   = (const float*)d_in[7];
    const float* out_b   = (const float*)d_in[8];
    const float* ln2_s   = (const float*)d_in[9];
    const float* ln2_b   = (const float*)d_in[10];
    const float* w1      = (const float*)d_in[11];
    const float* b1      = (const float*)d_in[12];
    const float* w2      = (const float*)d_in[13];
    const float* b2      = (const float*)d_in[14];
    const float* lnf_s   = (const float*)d_in[15];
    const float* lnf_b   = (const float*)d_in[16];
    const float* lm_w    = (const float*)d_in[17];

    char* ws = (char*)d_ws;
    float* x    = (float*)ws;  ws += (size_t)2048 * 1024 * 4;
    bf16*  h    = (bf16*)ws;   ws += (size_t)2048 * 1024 * 2;
    bf16*  qkvb = (bf16*)ws;   ws += (size_t)2048 * 3072 * 2;
    bf16*  attno= (bf16*)ws;   ws += (size_t)2048 * 1024 * 2;
    bf16*  vT   = (bf16*)ws;   ws += (size_t)32 * 64 * 1024 * 2;
    bf16*  ff   = (bf16*)ws;   ws += (size_t)2048 * 4096 * 2;
    bf16*  wTq2 = (bf16*)ws;   ws += (size_t)2 * 3072 * 1024 * 2;
    bf16*  wTo_all = (bf16*)ws; ws += (size_t)6 * 1024 * 1024 * 2;
    bf16*  wT1  = (bf16*)ws;   ws += (size_t)4096 * 1024 * 2;
    bf16*  wT2  = (bf16*)ws;   ws += (size_t)1024 * 4096 * 2;
    bf16*  wTlm = (bf16*)ws;   ws += (size_t)32000 * 1024 * 2;
    int*   cnts = (int*)ws;    ws += (size_t)6 * 16 * 4;

    for (int l = 0; l < 6; l++) {
        bf16* wTq_cur = wTq2 + (size_t)(l & 1) * 3072 * 1024;
        bf16* wTq_nxt = wTq2 + (size_t)((l + 1) & 1) * 3072 * 1024;
        if (l == 0) {
            front_kernel<<<2816, 256, 0, stream>>>(
                ids, tok_emb, pos_emb, x, ln1_s, ln1_b, h, qkv_w, wTq_cur);
        }
        // h for l>=1 produced by previous layer's fused mlp2+LN
        gemm256_kernel<128,192,4,1><<<256, 512, 81920, stream>>>(
            h, wTq_cur, qkv_b + l*3072, nullptr, qkvb, nullptr, vT, 3072, 1024);
        const int nbq = (l < 5) ? 768 : 0;
        const int lm_lo = (8000 * l) / 6;
        const int lm_cnt = (8000 * (l + 1)) / 6 - lm_lo;
        attn_wcvt_kernel<<<512 + nbq + 1024 + 1024 + 256 + lm_cnt, 256, 0, stream>>>(
            qkvb, vT, attno,
            (l < 5) ? qkv_w + (size_t)(l+1)*1024*3072 : nullptr, wTq_nxt, nbq,
            w1 + (size_t)l*1024*4096, wT1,
            w2 + (size_t)l*4096*1024, wT2,
            out_w + (size_t)l*1024*1024, wTo_all + (size_t)l*1024*1024,
            lm_w, wTlm, lm_lo);
        gemm256_kernel<128,256,1,4><<<256, 512, 98304, stream>>>(
            attno, wTo_all + (size_t)l*1024*1024, out_b + l*1024, x, nullptr, nullptr, nullptr, 1024, 1024);
        ln_kernel<<<2048, 256, 0, stream>>>(x, ln2_s + l*1024, ln2_b + l*1024, h, cnts + l*16);
        gemm256_kernel<128,256,2,1><<<256, 512, 98304, stream>>>(
            h, wT1, b1 + l*4096, nullptr, ff, nullptr, nullptr, 4096, 1024);
        // mlp2 + fused LN (ln1[l+1] for l<5, lnf for l=5) -> h ready for next dispatch
        gemm_mlp2ln_kernel<<<256, 512, 98304, stream>>>(
            ff, wT2, b2 + l*1024, x, cnts + l*16,
            (l < 5) ? ln1_s + (l+1)*1024 : lnf_s,
            (l < 5) ? ln1_b + (l+1)*1024 : lnf_b,
            h, 1024, 4096);
    }
    gemm256_kernel<256,256,3,1><<<8*125, 512, 131072, stream>>>(
        h, wTlm, nullptr, nullptr, nullptr, (float*)d_out, nullptr, 32000, 1024);
}

// Round 20
// 1225.073 us; speedup vs baseline: 1.3797x; 1.3797x over previous
//
#include <hip/hip_runtime.h>
#include <hip/hip_bf16.h>
#include <cstdint>
#include <cstddef>

typedef __bf16 bf16;
typedef __attribute__((ext_vector_type(8))) __bf16 bf16x8;
typedef __attribute__((ext_vector_type(4))) __bf16 bf16x4;
typedef __attribute__((ext_vector_type(4))) float f32x4;

__device__ __forceinline__ f32x4 mfma16(bf16x8 a, bf16x8 b, f32x4 c) {
    return __builtin_amdgcn_mfma_f32_16x16x32_bf16(a, b, c, 0, 0, 0);
}

__device__ __forceinline__ void async_copy16(const void* g, void* l) {
    __builtin_amdgcn_global_load_lds((const __attribute__((address_space(1))) void*)g,
                                     (__attribute__((address_space(3))) void*)l,
                                     16, 0, 0);
}

template<int Ncnt> __device__ __forceinline__ void waitv();
template<> __device__ __forceinline__ void waitv<0>() { asm volatile("s_waitcnt vmcnt(0)" ::: "memory"); }
template<> __device__ __forceinline__ void waitv<2>() { asm volatile("s_waitcnt vmcnt(2)" ::: "memory"); }
template<> __device__ __forceinline__ void waitv<3>() { asm volatile("s_waitcnt vmcnt(3)" ::: "memory"); }
template<> __device__ __forceinline__ void waitv<4>() { asm volatile("s_waitcnt vmcnt(4)" ::: "memory"); }

__device__ __forceinline__ void wait_g(int n) {
    if (n == 2) waitv<2>();
    else if (n == 3) waitv<3>();
    else waitv<4>();
}

// ---------------- device bodies ----------------
__device__ __forceinline__ void ln_vec(f32x4 v, const float* __restrict__ sc,
                                       const float* __restrict__ bi, bf16* __restrict__ out,
                                       int row, int t, float* red)
{
    float s = v[0] + v[1] + v[2] + v[3];
    float q = v[0]*v[0] + v[1]*v[1] + v[2]*v[2] + v[3]*v[3];
    #pragma unroll
    for (int o = 1; o < 64; o <<= 1) { s += __shfl_xor(s, o); q += __shfl_xor(q, o); }
    const int wv = t >> 6, lane = t & 63;
    if (lane == 0) { red[wv] = s; red[4 + wv] = q; }
    __syncthreads();
    s = red[0] + red[1] + red[2] + red[3];
    q = red[4] + red[5] + red[6] + red[7];
    const float mean = s * (1.f / 1024.f);
    const float var  = q * (1.f / 1024.f) - mean * mean;
    const float rstd = rsqrtf(var + 1e-5f);
    const f32x4 scv = ((const f32x4*)sc)[t];
    const f32x4 biv = ((const f32x4*)bi)[t];
    bf16x4 o4;
    #pragma unroll
    for (int j = 0; j < 4; j++) o4[j] = (bf16)((v[j] - mean) * rstd * scv[j] + biv[j]);
    *(bf16x4*)(out + (size_t)row * 1024 + t * 4) = o4;
}

__device__ __forceinline__ void ln_body(const float* __restrict__ x, const float* __restrict__ sc,
                                        const float* __restrict__ bi, bf16* __restrict__ out,
                                        int row, int t, float* red)
{
    const f32x4 v = ((const f32x4*)(x + (size_t)row * 1024))[t];
    ln_vec(v, sc, bi, out, row, t, red);
}

__device__ __forceinline__ void wcvt_body(const float* __restrict__ W, bf16* __restrict__ BT,
                                          int K, int N, int bid, int tidx, float (*tile)[65])
{
    const int nx = N >> 6;
    const int n0 = (bid % nx) << 6, k0 = (bid / nx) << 6;
    const int tx = tidx & 15, ty = tidx >> 4;
    #pragma unroll
    for (int r = 0; r < 4; r++) {
        const f32x4 v = *(const f32x4*)&W[(size_t)(k0 + ty + r*16) * N + n0 + tx*4];
        tile[ty + r*16][tx*4 + 0] = v[0];
        tile[ty + r*16][tx*4 + 1] = v[1];
        tile[ty + r*16][tx*4 + 2] = v[2];
        tile[ty + r*16][tx*4 + 3] = v[3];
    }
    __syncthreads();
    #pragma unroll
    for (int r = 0; r < 4; r++) {
        const int n = ty + r*16;
        bf16x4 o;
        #pragma unroll
        for (int j = 0; j < 4; j++) o[j] = (bf16)tile[tx*4 + j][n];
        *(bf16x4*)&BT[(size_t)(n0 + n) * K + k0 + tx*4] = o;
    }
}

// ---------------- slim front: embed+ln1(l0) + wcvt qkv(l0) only ----------------
__global__ __launch_bounds__(256)
void front_kernel(const int* __restrict__ ids, const float* __restrict__ te,
                  const float* __restrict__ pe, float* __restrict__ x,
                  const float* __restrict__ sc, const float* __restrict__ bi,
                  bf16* __restrict__ out,
                  const float* __restrict__ qkvw0, bf16* __restrict__ wTq)
{
    __shared__ float tile[64][65];
    __shared__ float red[8];
    const int bid = blockIdx.x, t = threadIdx.x;
    if (bid < 2048) {
        const int s = bid & 1023;
        const int id = ids[bid];
        const f32x4 a = ((const f32x4*)(te + (size_t)id * 1024))[t];
        const f32x4 b = ((const f32x4*)(pe + (size_t)s * 1024))[t];
        const f32x4 v = a + b;
        ((f32x4*)(x + (size_t)bid * 1024))[t] = v;
        ln_vec(v, sc, bi, out, bid, t, red);
    } else {
        wcvt_body(qkvw0, wTq, 1024, 3072, bid - 2048, t, tile);
    }
}

// ---------------- LN-only dispatch ----------------
__global__ __launch_bounds__(256)
void ln_kernel(const float* __restrict__ x, const float* __restrict__ sc,
               const float* __restrict__ bi, bf16* __restrict__ out)
{
    __shared__ float red[8];
    ln_body(x, sc, bi, out, blockIdx.x, threadIdx.x, red);
}

// ---------------- fused attention + ALL off-critical-path weight converts ----------------
// blocks [0,512): attn.  Then: nbq x qkv_w[l+1] | 1024 x w1[l] | 1024 x w2[l] |
// 256 x out_w[l] | lm_cnt x lm_w slice [lm_lo, lm_lo+lm_cnt).
__global__ __launch_bounds__(256)
void attn_wcvt_kernel(const bf16* __restrict__ qkv, const bf16* __restrict__ vT,
                      bf16* __restrict__ attno,
                      const float* __restrict__ qkvw_n, bf16* __restrict__ wTq_n, int nbq,
                      const float* __restrict__ w1, bf16* __restrict__ wT1,
                      const float* __restrict__ w2, bf16* __restrict__ wT2,
                      const float* __restrict__ outw, bf16* __restrict__ wTo,
                      const float* __restrict__ lmw, bf16* __restrict__ wTlm, int lm_lo)
{
    __shared__ __align__(16) char smem[49664];
    const int bid = blockIdx.x, tid = threadIdx.x;

    if (bid >= 512) {
        float (*tile)[65] = (float(*)[65])smem;
        int wb = bid - 512;
        if (wb < nbq) { wcvt_body(qkvw_n, wTq_n, 1024, 3072, wb, tid, tile); return; }
        wb -= nbq;
        if (wb < 1024) { wcvt_body(w1, wT1, 1024, 4096, wb, tid, tile); return; }
        wb -= 1024;
        if (wb < 1024) { wcvt_body(w2, wT2, 4096, 1024, wb, tid, tile); return; }
        wb -= 1024;
        if (wb < 256)  { wcvt_body(outw, wTo, 1024, 1024, wb, tid, tile); return; }
        wb -= 256;
        wcvt_body(lmw, wTlm, 1024, 32000, lm_lo + wb, tid, tile);
        return;
    }

    bf16* Ksh = (bf16*)smem;                 // [128*64]
    bf16* Vt  = (bf16*)(smem + 16384);       // [64*128]
    bf16* Plds = (bf16*)(smem + 32768);      // [4][16][132]
#define PLDS(w_, r_, c_) Plds[(((w_) << 4) + (r_)) * 132 + (c_)]

    const int b = (bid & 31) >> 4, h = bid & 15;
    const int qb = bid >> 5;
    const int lane = tid & 63, wave = tid >> 6;
    const bf16* base = qkv + (size_t)b * 1024 * 3072;
    const bf16* vbase = vT + (size_t)(b*16 + h) * 64 * 1024;
    const int qrow0 = qb * 64 + wave * 16;
    const int l15 = lane & 15;

    bf16x8 aQ[2];
    {
        const int qr = qrow0 + l15;
        const bf16* qp = base + (size_t)qr * 3072 + h * 64 + ((lane >> 4) << 3);
        aQ[0] = *(const bf16x8*)qp;
        aQ[1] = *(const bf16x8*)(qp + 32);
    }
    float m_i[4] = {-1e30f, -1e30f, -1e30f, -1e30f};
    float l_i[4] = {0.f, 0.f, 0.f, 0.f};
    f32x4 acc[4];
    #pragma unroll
    for (int nb = 0; nb < 4; nb++) acc[nb] = f32x4{0.f, 0.f, 0.f, 0.f};

    const int swzA = (((lane >> 4)     ^ (lane & 7)) << 3);
    const int swzB = (((4 + (lane >> 4)) ^ (lane & 7)) << 3);

    for (int ck = 0; ck < 8; ck++) {
        __syncthreads();   // WAR drain on Ksh/Vt before restaging
        #pragma unroll
        for (int p = 0; p < 4; p++) {
            const int c = p * 256 + tid;
            const int rw = c >> 3;
            const int kc = (c & 7) ^ (rw & 7);
            async_copy16(base + (size_t)(ck*128 + rw) * 3072 + 1024 + h*64 + kc*8, &Ksh[c * 8]);
        }
        #pragma unroll
        for (int p = 0; p < 4; p++) {
            const int c = p * 256 + tid;
            const int rw = c >> 4;
            const int kc = (c & 15) ^ (rw & 7);
            async_copy16(vbase + (size_t)rw * 1024 + ck*128 + kc*8, &Vt[c * 8]);
        }
        waitv<4>();                                   // K landed (V still in flight)
        __builtin_amdgcn_sched_barrier(0);
        __builtin_amdgcn_s_barrier();                 // K visible

        f32x4 sc[8];
        #pragma unroll
        for (int kk = 0; kk < 4; kk++) {
            const int kr0 = (kk*32 + l15) * 64;
            const int kr1 = kr0 + 16*64;
            f32x4 z{0.f, 0.f, 0.f, 0.f};
            z = mfma16(aQ[0], *(const bf16x8*)&Ksh[kr0 + swzA], z);
            z = mfma16(aQ[1], *(const bf16x8*)&Ksh[kr0 + swzB], z);
            sc[2*kk] = z;
            f32x4 z2{0.f, 0.f, 0.f, 0.f};
            z2 = mfma16(aQ[0], *(const bf16x8*)&Ksh[kr1 + swzA], z2);
            z2 = mfma16(aQ[1], *(const bf16x8*)&Ksh[kr1 + swzB], z2);
            sc[2*kk+1] = z2;
        }

        float c[4];
        #pragma unroll
        for (int i = 0; i < 4; i++) {
            float t = sc[0][i];
            #pragma unroll
            for (int e = 1; e < 8; e++) t = fmaxf(t, sc[e][i]);
            #pragma unroll
            for (int o = 1; o < 16; o <<= 1) t = fmaxf(t, __shfl_xor(t, o));
            t *= 0.125f;
            const float mnew = fmaxf(m_i[i], t);
            c[i] = __expf(m_i[i] - mnew);
            float p[8];
            float rs = 0.f;
            #pragma unroll
            for (int e = 0; e < 8; e++) {
                p[e] = __expf(fmaf(sc[e][i], 0.125f, -mnew));
                rs += p[e];
            }
            #pragma unroll
            for (int o = 1; o < 16; o <<= 1) rs += __shfl_xor(rs, o);
            l_i[i] = l_i[i] * c[i] + rs;
            m_i[i] = mnew;
            const int pr = ((lane >> 4) << 2) + i;
            #pragma unroll
            for (int e = 0; e < 8; e++)
                PLDS(wave, pr, (e >> 1) * 32 + (e & 1) * 16 + l15) = (bf16)p[e];
        }

        waitv<0>();                                   // V landed (hidden under QK+softmax)
        __builtin_amdgcn_sched_barrier(0);
        __builtin_amdgcn_s_barrier();                 // V visible

        #pragma unroll
        for (int nb = 0; nb < 4; nb++) {
            f32x4 a = acc[nb];
            a[0] *= c[0]; a[1] *= c[1]; a[2] *= c[2]; a[3] *= c[3];
            acc[nb] = a;
        }
        #pragma unroll
        for (int kk = 0; kk < 4; kk++) {
            const bf16x8 aP = *(const bf16x8*)&PLDS(wave, l15, kk*32 + ((lane >> 4) << 3));
            #pragma unroll
            for (int nb = 0; nb < 4; nb++) {
                const int r = nb*16 + l15;
                const int chk = (kk*4 + (lane >> 4)) ^ (r & 7);
                const bf16x8 bV = *(const bf16x8*)&Vt[r*128 + chk*8];
                acc[nb] = mfma16(aP, bV, acc[nb]);
            }
        }
    }
    #pragma unroll
    for (int nb = 0; nb < 4; nb++) {
        #pragma unroll
        for (int i = 0; i < 4; i++) {
            const int row = qrow0 + ((lane >> 4) << 2) + i;
            const float o = acc[nb][i] / l_i[i];
            attno[(size_t)(b*1024 + row) * 1024 + h*64 + nb*16 + l15] = (bf16)o;
        }
    }
#undef PLDS
}

// ---------------- 8-phase GEMM (T3+T4), generalized BN ----------------
// EPI: 0 bias->bf16 ; 1 bias+resid f32 (atomic if KSPLIT>1) ; 2 bias+gelu->bf16 ; 3 f32 ;
//      4 qkv-special: cols<2048 -> bf16 qkvb, V cols -> transposed bf16x4 into vt
template<int BM, int BN, int EPI, int KSPLIT>
__global__ __launch_bounds__(512, 2)
void gemm256_kernel(const bf16* __restrict__ A, const bf16* __restrict__ BT,
                    const float* __restrict__ bias, float* __restrict__ resid,
                    bf16* __restrict__ outb, float* __restrict__ outf,
                    bf16* __restrict__ vt, int N, int K)
{
    constexpr int MT = 2048 / BM;
    constexpr int FM = BM / 32;
    constexpr int FN = BN / 64;
    constexpr int HM = FM / 2;
    constexpr int ACH = BM * 4;
    constexpr int BCH = BN * 4;
    constexpr int LA = (ACH + 511) >> 9;
    constexpr int LB = (BCH + 511) >> 9;
    constexpr int ASUB = BM * 32;
    constexpr int BSUB = BN * 32;
    extern __shared__ __align__(16) char smem_raw[];
    bf16* smem = (bf16*)smem_raw;

    const int nwg = gridDim.x;
    const int q = nwg >> 3, rr = nwg & 7;
    const int xcd = blockIdx.x & 7, ix = blockIdx.x >> 3;
    const int nid = (xcd < rr ? xcd * (q + 1) : rr * (q + 1) + (xcd - rr) * q) + ix;
    const int tiles = nwg / KSPLIT;
    const int ks = nid / tiles;
    const int tile = nid % tiles;
    const int bm = tile % MT, bn = tile / MT;

    const int tid = threadIdx.x, lane = tid & 63, wave = tid >> 6;
    const int wr = wave >> 2, wc = wave & 3;

    const int myB = ((BCH & 511) == 0) ? (BCH >> 9)
                    : ((tid < (BCH & 511)) ? (BCH >> 9) + 1 : (BCH >> 9));
    const int wcount = LA + myB;

    f32x4 acc[FM][FN];
    #pragma unroll
    for (int m = 0; m < FM; m++)
        #pragma unroll
        for (int n = 0; n < FN; n++) acc[m][n] = f32x4{0.f, 0.f, 0.f, 0.f};

    const bf16* Abase = A  + (size_t)bm * BM * K;
    const bf16* Bbase = BT + (size_t)bn * BN * K;
    const int Ts = (K >> 6) / KSPLIT;
    const int t0 = ks * Ts;

    const int l15 = lane & 15;
    const int swz = (((lane >> 4) ^ ((l15 >> 1) & 3)) << 3);
    const int arow0 = wr * (BM / 2) + l15;
    const int brow0 = wc * (BN / 4) + l15;

#define ABASE_(p_, ks_) (((p_)*2 + (ks_)) * ASUB)
#define BBASE_(p_, ks_) (4*ASUB + ((p_)*2 + (ks_)) * BSUB)
#define STAGE_A(p_, kt_, ks_) { _Pragma("unroll") for (int i = 0; i < LA; i++) { \
    const int c = tid + i * 512; \
    if ((ACH & 511) == 0 || c < ACH) { \
      const int rw = c >> 2; \
      const int kc = (c & 3) ^ ((rw >> 1) & 3); \
      async_copy16(Abase + (size_t)rw * K + (kt_)*64 + (ks_)*32 + kc*8, \
                   &smem[ABASE_(p_, ks_) + c*8]); } } }
#define STAGE_B(p_, kt_, ks_) { _Pragma("unroll") for (int i = 0; i < LB; i++) { \
    const int c = tid + i * 512; \
    if ((BCH & 511) == 0 || c < BCH) { \
      const int rw = c >> 2; \
      const int kc = (c & 3) ^ ((rw >> 1) & 3); \
      async_copy16(Bbase + (size_t)rw * K + (kt_)*64 + (ks_)*32 + kc*8, \
                   &smem[BBASE_(p_, ks_) + c*8]); } } }
#define LOAD_B(p_, ks_) { _Pragma("unroll") for (int n = 0; n < FN; n++) \
    bfv[n] = *(const bf16x8*)&smem[BBASE_(p_, ks_) + (brow0 + n*16)*32 + swz]; }
#define LOAD_A(p_, ks_, mg) { _Pragma("unroll") for (int m = 0; m < HM; m++) \
    af[m] = *(const bf16x8*)&smem[ABASE_(p_, ks_) + (arow0 + ((mg)*HM + m)*16)*32 + swz]; }
#define QUAD(mg) { __builtin_amdgcn_s_setprio(1); \
    _Pragma("unroll") for (int m = 0; m < HM; m++) \
      _Pragma("unroll") for (int n = 0; n < FN; n++) \
        acc[(mg)*HM + m][n] = mfma16(af[m], bfv[n], acc[(mg)*HM + m][n]); \
    __builtin_amdgcn_s_setprio(0); }

    STAGE_A(0, t0, 0); STAGE_B(0, t0, 0); STAGE_A(0, t0, 1); STAGE_B(0, t0, 1);
    wait_g(wcount);
    __builtin_amdgcn_s_barrier();

    for (int tl = 0; tl < Ts; tl++) {
        const int b = tl & 1;
        const int kt1 = t0 + tl + 1;
        const bool more = (tl + 1) < Ts;
        bf16x8 af[HM], bfv[FN];
        LOAD_B(b, 0); LOAD_A(b, 0, 0);
        if (more) STAGE_A(b ^ 1, kt1, 0);
        __builtin_amdgcn_s_barrier();
        QUAD(0);
        __builtin_amdgcn_s_barrier();
        LOAD_A(b, 0, 1);
        if (more) STAGE_B(b ^ 1, kt1, 0);
        __builtin_amdgcn_s_barrier();
        QUAD(1);
        if (more) wait_g(wcount); else waitv<0>();
        __builtin_amdgcn_s_barrier();
        LOAD_B(b, 1); LOAD_A(b, 1, 0);
        if (more) STAGE_A(b ^ 1, kt1, 1);
        __builtin_amdgcn_s_barrier();
        QUAD(0);
        __builtin_amdgcn_s_barrier();
        LOAD_A(b, 1, 1);
        if (more) STAGE_B(b ^ 1, kt1, 1);
        __builtin_amdgcn_s_barrier();
        QUAD(1);
        if (more) wait_g(wcount);
        __builtin_amdgcn_s_barrier();
    }

    const int er = bm * BM + wr * (BM / 2) + ((lane >> 4) << 2);
    const int ec = bn * BN + wc * (BN / 4) + l15;
    #pragma unroll
    for (int n = 0; n < FN; n++) {
        const int col = ec + n * 16;
        const float bv = (EPI == 3) ? 0.f : ((KSPLIT > 1 && ks != 0) ? 0.f : bias[col]);
        #pragma unroll
        for (int m = 0; m < FM; m++) {
            const int row0 = er + m * 16;
            if constexpr (EPI == 4) {
                if (col < 2048) {
                    #pragma unroll
                    for (int i = 0; i < 4; i++)
                        outb[(size_t)(row0 + i) * N + col] = (bf16)(acc[m][n][i] + bv);
                } else {
                    bf16x4 o4;
                    #pragma unroll
                    for (int i = 0; i < 4; i++) o4[i] = (bf16)(acc[m][n][i] + bv);
                    const int b_ = row0 >> 10, tok = row0 & 1023;
                    *(bf16x4*)&vt[((size_t)(b_ * 1024 + (col - 2048))) * 1024 + tok] = o4;
                }
            } else {
                #pragma unroll
                for (int i = 0; i < 4; i++) {
                    const float v = acc[m][n][i] + bv;
                    const size_t off = (size_t)(row0 + i) * N + col;
                    if constexpr (EPI == 0) outb[off] = (bf16)v;
                    else if constexpr (EPI == 1) {
                        if constexpr (KSPLIT > 1) atomicAdd(&resid[off], v);
                        else resid[off] += v;
                    }
                    else if constexpr (EPI == 2) {
                        outb[off] = (bf16)(0.5f * v * (1.f + erff(v * 0.70710678118f)));
                    } else {
                        outf[off] = v;
                    }
                }
            }
        }
    }
#undef ABASE_
#undef BBASE_
#undef STAGE_A
#undef STAGE_B
#undef LOAD_A
#undef LOAD_B
#undef QUAD
}

// ---------------- orchestration ----------------
extern "C" void kernel_launch(void* const* d_in, const int* in_sizes, int n_in,
                              void* d_out, int out_size, void* d_ws, size_t ws_size,
                              hipStream_t stream)
{
    const int*   ids     = (const int*)  d_in[0];
    const float* tok_emb = (const float*)d_in[1];
    const float* pos_emb = (const float*)d_in[2];
    const float* ln1_s   = (const float*)d_in[3];
    const float* ln1_b   = (const float*)d_in[4];
    const float* qkv_w   = (const float*)d_in[5];
    const float* qkv_b   = (const float*)d_in[6];
    const float* out_w   = (const float*)d_in[7];
    const float* out_b   = (const float*)d_in[8];
    const float* ln2_s   = (const float*)d_in[9];
    const float* ln2_b   = (const float*)d_in[10];
    const float* w1      = (const float*)d_in[11];
    const float* b1      = (const float*)d_in[12];
    const float* w2      = (const float*)d_in[13];
    const float* b2      = (const float*)d_in[14];
    const float* lnf_s   = (const float*)d_in[15];
    const float* lnf_b   = (const float*)d_in[16];
    const float* lm_w    = (const float*)d_in[17];

    char* ws = (char*)d_ws;
    float* x    = (float*)ws;  ws += (size_t)2048 * 1024 * 4;
    bf16*  h    = (bf16*)ws;   ws += (size_t)2048 * 1024 * 2;
    bf16*  qkvb = (bf16*)ws;   ws += (size_t)2048 * 3072 * 2;
    bf16*  attno= (bf16*)ws;   ws += (size_t)2048 * 1024 * 2;
    bf16*  vT   = (bf16*)ws;   ws += (size_t)32 * 64 * 1024 * 2;
    bf16*  ff   = (bf16*)ws;   ws += (size_t)2048 * 4096 * 2;
    bf16*  wTq2 = (bf16*)ws;   ws += (size_t)2 * 3072 * 1024 * 2;   // double-buffered
    bf16*  wTo_all = (bf16*)ws; ws += (size_t)6 * 1024 * 1024 * 2;
    bf16*  wT1  = (bf16*)ws;   ws += (size_t)4096 * 1024 * 2;
    bf16*  wT2  = (bf16*)ws;   ws += (size_t)1024 * 4096 * 2;
    bf16*  wTlm = (bf16*)ws;   ws += (size_t)32000 * 1024 * 2;

    for (int l = 0; l < 6; l++) {
        bf16* wTq_cur = wTq2 + (size_t)(l & 1) * 3072 * 1024;
        bf16* wTq_nxt = wTq2 + (size_t)((l + 1) & 1) * 3072 * 1024;
        if (l == 0) {
            front_kernel<<<2816, 256, 0, stream>>>(
                ids, tok_emb, pos_emb, x, ln1_s, ln1_b, h, qkv_w, wTq_cur);
        } else {
            ln_kernel<<<2048, 256, 0, stream>>>(x, ln1_s + l*1024, ln1_b + l*1024, h);
        }
        gemm256_kernel<128,192,4,1><<<256, 512, 81920, stream>>>(
            h, wTq_cur, qkv_b + l*3072, nullptr, qkvb, nullptr, vT, 3072, 1024);
        // attn + qkv[l+1] + w1[l] + w2[l] + out_w[l] + lm_w slice (all off critical path)
        const int nbq = (l < 5) ? 768 : 0;
        const int lm_lo = (8000 * l) / 6;
        const int lm_cnt = (8000 * (l + 1)) / 6 - lm_lo;
        attn_wcvt_kernel<<<512 + nbq + 1024 + 1024 + 256 + lm_cnt, 256, 0, stream>>>(
            qkvb, vT, attno,
            (l < 5) ? qkv_w + (size_t)(l+1)*1024*3072 : nullptr, wTq_nxt, nbq,
            w1 + (size_t)l*1024*4096, wT1,
            w2 + (size_t)l*4096*1024, wT2,
            out_w + (size_t)l*1024*1024, wTo_all + (size_t)l*1024*1024,
            lm_w, wTlm, lm_lo);
        gemm256_kernel<128,256,1,4><<<256, 512, 98304, stream>>>(
            attno, wTo_all + (size_t)l*1024*1024, out_b + l*1024, x, nullptr, nullptr, nullptr, 1024, 1024);
        ln_kernel<<<2048, 256, 0, stream>>>(x, ln2_s + l*1024, ln2_b + l*1024, h);
        gemm256_kernel<128,256,2,1><<<256, 512, 98304, stream>>>(
            h, wT1, b1 + l*4096, nullptr, ff, nullptr, nullptr, 4096, 1024);
        gemm256_kernel<128,256,1,4><<<256, 512, 98304, stream>>>(
            ff, wT2, b2 + l*1024, x, nullptr, nullptr, nullptr, 1024, 4096);
    }
    ln_kernel<<<2048, 256, 0, stream>>>(x, lnf_s, lnf_b, h);
    gemm256_kernel<256,256,3,1><<<8*125, 512, 131072, stream>>>(
        h, wTlm, nullptr, nullptr, nullptr, (float*)d_out, nullptr, 32000, 1024);
}

// Round 21
// 1113.373 us; speedup vs baseline: 1.5182x; 1.1003x over previous
//
#include <hip/hip_runtime.h>
#include <hip/hip_bf16.h>
#include <cstdint>
#include <cstddef>

typedef __bf16 bf16;
typedef __attribute__((ext_vector_type(8))) __bf16 bf16x8;
typedef __attribute__((ext_vector_type(4))) __bf16 bf16x4;
typedef __attribute__((ext_vector_type(4))) float f32x4;

__device__ __forceinline__ f32x4 mfma16(bf16x8 a, bf16x8 b, f32x4 c) {
    return __builtin_amdgcn_mfma_f32_16x16x32_bf16(a, b, c, 0, 0, 0);
}

__device__ __forceinline__ void async_copy16(const void* g, void* l) {
    __builtin_amdgcn_global_load_lds((const __attribute__((address_space(1))) void*)g,
                                     (__attribute__((address_space(3))) void*)l,
                                     16, 0, 0);
}

template<int Ncnt> __device__ __forceinline__ void waitv();
template<> __device__ __forceinline__ void waitv<0>() { asm volatile("s_waitcnt vmcnt(0)" ::: "memory"); }
template<> __device__ __forceinline__ void waitv<2>() { asm volatile("s_waitcnt vmcnt(2)" ::: "memory"); }
template<> __device__ __forceinline__ void waitv<3>() { asm volatile("s_waitcnt vmcnt(3)" ::: "memory"); }
template<> __device__ __forceinline__ void waitv<4>() { asm volatile("s_waitcnt vmcnt(4)" ::: "memory"); }

__device__ __forceinline__ void wait_g(int n) {
    if (n == 2) waitv<2>();
    else if (n == 3) waitv<3>();
    else waitv<4>();
}

// ---------------- device bodies ----------------
__device__ __forceinline__ void ln_vec(f32x4 v, const float* __restrict__ sc,
                                       const float* __restrict__ bi, bf16* __restrict__ out,
                                       int row, int t, float* red)
{
    float s = v[0] + v[1] + v[2] + v[3];
    float q = v[0]*v[0] + v[1]*v[1] + v[2]*v[2] + v[3]*v[3];
    #pragma unroll
    for (int o = 1; o < 64; o <<= 1) { s += __shfl_xor(s, o); q += __shfl_xor(q, o); }
    const int wv = t >> 6, lane = t & 63;
    if (lane == 0) { red[wv] = s; red[4 + wv] = q; }
    __syncthreads();
    s = red[0] + red[1] + red[2] + red[3];
    q = red[4] + red[5] + red[6] + red[7];
    const float mean = s * (1.f / 1024.f);
    const float var  = q * (1.f / 1024.f) - mean * mean;
    const float rstd = rsqrtf(var + 1e-5f);
    const f32x4 scv = ((const f32x4*)sc)[t];
    const f32x4 biv = ((const f32x4*)bi)[t];
    bf16x4 o4;
    #pragma unroll
    for (int j = 0; j < 4; j++) o4[j] = (bf16)((v[j] - mean) * rstd * scv[j] + biv[j]);
    *(bf16x4*)(out + (size_t)row * 1024 + t * 4) = o4;
}

__device__ __forceinline__ void ln_body(const float* __restrict__ x, const float* __restrict__ sc,
                                        const float* __restrict__ bi, bf16* __restrict__ out,
                                        int row, int t, float* red)
{
    const f32x4 v = ((const f32x4*)(x + (size_t)row * 1024))[t];
    ln_vec(v, sc, bi, out, row, t, red);
}

__device__ __forceinline__ void wcvt_body(const float* __restrict__ W, bf16* __restrict__ BT,
                                          int K, int N, int bid, int tidx, float (*tile)[65])
{
    const int nx = N >> 6;
    const int n0 = (bid % nx) << 6, k0 = (bid / nx) << 6;
    const int tx = tidx & 15, ty = tidx >> 4;
    #pragma unroll
    for (int r = 0; r < 4; r++) {
        const f32x4 v = *(const f32x4*)&W[(size_t)(k0 + ty + r*16) * N + n0 + tx*4];
        tile[ty + r*16][tx*4 + 0] = v[0];
        tile[ty + r*16][tx*4 + 1] = v[1];
        tile[ty + r*16][tx*4 + 2] = v[2];
        tile[ty + r*16][tx*4 + 3] = v[3];
    }
    __syncthreads();
    #pragma unroll
    for (int r = 0; r < 4; r++) {
        const int n = ty + r*16;
        bf16x4 o;
        #pragma unroll
        for (int j = 0; j < 4; j++) o[j] = (bf16)tile[tx*4 + j][n];
        *(bf16x4*)&BT[(size_t)(n0 + n) * K + k0 + tx*4] = o;
    }
}

// ---------------- slim front: embed+ln1(l0) + wcvt qkv(l0) only ----------------
__global__ __launch_bounds__(256)
void front_kernel(const int* __restrict__ ids, const float* __restrict__ te,
                  const float* __restrict__ pe, float* __restrict__ x,
                  const float* __restrict__ sc, const float* __restrict__ bi,
                  bf16* __restrict__ out,
                  const float* __restrict__ qkvw0, bf16* __restrict__ wTq)
{
    __shared__ float tile[64][65];
    __shared__ float red[8];
    const int bid = blockIdx.x, t = threadIdx.x;
    if (bid < 2048) {
        const int s = bid & 1023;
        const int id = ids[bid];
        const f32x4 a = ((const f32x4*)(te + (size_t)id * 1024))[t];
        const f32x4 b = ((const f32x4*)(pe + (size_t)s * 1024))[t];
        const f32x4 v = a + b;
        ((f32x4*)(x + (size_t)bid * 1024))[t] = v;
        ln_vec(v, sc, bi, out, bid, t, red);
    } else {
        wcvt_body(qkvw0, wTq, 1024, 3072, bid - 2048, t, tile);
    }
}

// ---------------- LN-only dispatch ----------------
__global__ __launch_bounds__(256)
void ln_kernel(const float* __restrict__ x, const float* __restrict__ sc,
               const float* __restrict__ bi, bf16* __restrict__ out)
{
    __shared__ float red[8];
    ln_body(x, sc, bi, out, blockIdx.x, threadIdx.x, red);
}

// ---------------- fused attention + ALL off-critical-path weight converts ----------------
__global__ __launch_bounds__(256)
void attn_wcvt_kernel(const bf16* __restrict__ qkv, const bf16* __restrict__ vT,
                      bf16* __restrict__ attno,
                      const float* __restrict__ qkvw_n, bf16* __restrict__ wTq_n, int nbq,
                      const float* __restrict__ w1, bf16* __restrict__ wT1,
                      const float* __restrict__ w2, bf16* __restrict__ wT2,
                      const float* __restrict__ outw, bf16* __restrict__ wTo,
                      const float* __restrict__ lmw, bf16* __restrict__ wTlm, int lm_lo)
{
    __shared__ __align__(16) char smem[49664];
    const int bid = blockIdx.x, tid = threadIdx.x;

    if (bid >= 512) {
        float (*tile)[65] = (float(*)[65])smem;
        int wb = bid - 512;
        if (wb < nbq) { wcvt_body(qkvw_n, wTq_n, 1024, 3072, wb, tid, tile); return; }
        wb -= nbq;
        if (wb < 1024) { wcvt_body(w1, wT1, 1024, 4096, wb, tid, tile); return; }
        wb -= 1024;
        if (wb < 1024) { wcvt_body(w2, wT2, 4096, 1024, wb, tid, tile); return; }
        wb -= 1024;
        if (wb < 256)  { wcvt_body(outw, wTo, 1024, 1024, wb, tid, tile); return; }
        wb -= 256;
        wcvt_body(lmw, wTlm, 1024, 32000, lm_lo + wb, tid, tile);
        return;
    }

    bf16* Ksh = (bf16*)smem;
    bf16* Vt  = (bf16*)(smem + 16384);
    bf16* Plds = (bf16*)(smem + 32768);
#define PLDS(w_, r_, c_) Plds[(((w_) << 4) + (r_)) * 132 + (c_)]

    const int b = (bid & 31) >> 4, h = bid & 15;
    const int qb = bid >> 5;
    const int lane = tid & 63, wave = tid >> 6;
    const bf16* base = qkv + (size_t)b * 1024 * 3072;
    const bf16* vbase = vT + (size_t)(b*16 + h) * 64 * 1024;
    const int qrow0 = qb * 64 + wave * 16;
    const int l15 = lane & 15;

    bf16x8 aQ[2];
    {
        const int qr = qrow0 + l15;
        const bf16* qp = base + (size_t)qr * 3072 + h * 64 + ((lane >> 4) << 3);
        aQ[0] = *(const bf16x8*)qp;
        aQ[1] = *(const bf16x8*)(qp + 32);
    }
    float m_i[4] = {-1e30f, -1e30f, -1e30f, -1e30f};
    float l_i[4] = {0.f, 0.f, 0.f, 0.f};
    f32x4 acc[4];
    #pragma unroll
    for (int nb = 0; nb < 4; nb++) acc[nb] = f32x4{0.f, 0.f, 0.f, 0.f};

    const int swzA = (((lane >> 4)     ^ (lane & 7)) << 3);
    const int swzB = (((4 + (lane >> 4)) ^ (lane & 7)) << 3);

    for (int ck = 0; ck < 8; ck++) {
        __syncthreads();
        #pragma unroll
        for (int p = 0; p < 4; p++) {
            const int c = p * 256 + tid;
            const int rw = c >> 3;
            const int kc = (c & 7) ^ (rw & 7);
            async_copy16(base + (size_t)(ck*128 + rw) * 3072 + 1024 + h*64 + kc*8, &Ksh[c * 8]);
        }
        #pragma unroll
        for (int p = 0; p < 4; p++) {
            const int c = p * 256 + tid;
            const int rw = c >> 4;
            const int kc = (c & 15) ^ (rw & 7);
            async_copy16(vbase + (size_t)rw * 1024 + ck*128 + kc*8, &Vt[c * 8]);
        }
        waitv<4>();
        __builtin_amdgcn_sched_barrier(0);
        __builtin_amdgcn_s_barrier();

        f32x4 sc[8];
        #pragma unroll
        for (int kk = 0; kk < 4; kk++) {
            const int kr0 = (kk*32 + l15) * 64;
            const int kr1 = kr0 + 16*64;
            f32x4 z{0.f, 0.f, 0.f, 0.f};
            z = mfma16(aQ[0], *(const bf16x8*)&Ksh[kr0 + swzA], z);
            z = mfma16(aQ[1], *(const bf16x8*)&Ksh[kr0 + swzB], z);
            sc[2*kk] = z;
            f32x4 z2{0.f, 0.f, 0.f, 0.f};
            z2 = mfma16(aQ[0], *(const bf16x8*)&Ksh[kr1 + swzA], z2);
            z2 = mfma16(aQ[1], *(const bf16x8*)&Ksh[kr1 + swzB], z2);
            sc[2*kk+1] = z2;
        }

        float c[4];
        #pragma unroll
        for (int i = 0; i < 4; i++) {
            float t = sc[0][i];
            #pragma unroll
            for (int e = 1; e < 8; e++) t = fmaxf(t, sc[e][i]);
            #pragma unroll
            for (int o = 1; o < 16; o <<= 1) t = fmaxf(t, __shfl_xor(t, o));
            t *= 0.125f;
            const float mnew = fmaxf(m_i[i], t);
            c[i] = __expf(m_i[i] - mnew);
            float p[8];
            float rs = 0.f;
            #pragma unroll
            for (int e = 0; e < 8; e++) {
                p[e] = __expf(fmaf(sc[e][i], 0.125f, -mnew));
                rs += p[e];
            }
            #pragma unroll
            for (int o = 1; o < 16; o <<= 1) rs += __shfl_xor(rs, o);
            l_i[i] = l_i[i] * c[i] + rs;
            m_i[i] = mnew;
            const int pr = ((lane >> 4) << 2) + i;
            #pragma unroll
            for (int e = 0; e < 8; e++)
                PLDS(wave, pr, (e >> 1) * 32 + (e & 1) * 16 + l15) = (bf16)p[e];
        }

        waitv<0>();
        __builtin_amdgcn_sched_barrier(0);
        __builtin_amdgcn_s_barrier();

        #pragma unroll
        for (int nb = 0; nb < 4; nb++) {
            f32x4 a = acc[nb];
            a[0] *= c[0]; a[1] *= c[1]; a[2] *= c[2]; a[3] *= c[3];
            acc[nb] = a;
        }
        #pragma unroll
        for (int kk = 0; kk < 4; kk++) {
            const bf16x8 aP = *(const bf16x8*)&PLDS(wave, l15, kk*32 + ((lane >> 4) << 3));
            #pragma unroll
            for (int nb = 0; nb < 4; nb++) {
                const int r = nb*16 + l15;
                const int chk = (kk*4 + (lane >> 4)) ^ (r & 7);
                const bf16x8 bV = *(const bf16x8*)&Vt[r*128 + chk*8];
                acc[nb] = mfma16(aP, bV, acc[nb]);
            }
        }
    }
    #pragma unroll
    for (int nb = 0; nb < 4; nb++) {
        #pragma unroll
        for (int i = 0; i < 4; i++) {
            const int row = qrow0 + ((lane >> 4) << 2) + i;
            const float o = acc[nb][i] / l_i[i];
            attno[(size_t)(b*1024 + row) * 1024 + h*64 + nb*16 + l15] = (bf16)o;
        }
    }
#undef PLDS
}

// ---------------- 8-phase GEMM (T3+T4), generalized BN ----------------
// EPI: 0 bias->bf16 ; 1 bias+resid f32 (atomic if KSPLIT>1) ; 2 bias+gelu->bf16 ; 3 f32 ;
//      4 qkv-special: cols<2048 -> bf16 qkvb, V cols -> transposed bf16x4 into vt
template<int BM, int BN, int EPI, int KSPLIT>
__global__ __launch_bounds__(512, 2)
void gemm256_kernel(const bf16* __restrict__ A, const bf16* __restrict__ BT,
                    const float* __restrict__ bias, float* __restrict__ resid,
                    bf16* __restrict__ outb, float* __restrict__ outf,
                    bf16* __restrict__ vt, int N, int K)
{
    constexpr int MT = 2048 / BM;
    constexpr int FM = BM / 32;
    constexpr int FN = BN / 64;
    constexpr int HM = FM / 2;
    constexpr int ACH = BM * 4;
    constexpr int BCH = BN * 4;
    constexpr int LA = (ACH + 511) >> 9;
    constexpr int LB = (BCH + 511) >> 9;
    constexpr int ASUB = BM * 32;
    constexpr int BSUB = BN * 32;
    extern __shared__ __align__(16) char smem_raw[];
    bf16* smem = (bf16*)smem_raw;

    const int nwg = gridDim.x;
    const int q = nwg >> 3, rr = nwg & 7;
    const int xcd = blockIdx.x & 7, ix = blockIdx.x >> 3;
    const int nid = (xcd < rr ? xcd * (q + 1) : rr * (q + 1) + (xcd - rr) * q) + ix;
    const int tiles = nwg / KSPLIT;
    const int ks = nid / tiles;
    const int tile = nid % tiles;
    const int bm = tile % MT, bn = tile / MT;

    const int tid = threadIdx.x, lane = tid & 63, wave = tid >> 6;
    const int wr = wave >> 2, wc = wave & 3;

    const int myB = ((BCH & 511) == 0) ? (BCH >> 9)
                    : ((tid < (BCH & 511)) ? (BCH >> 9) + 1 : (BCH >> 9));
    const int wcount = LA + myB;

    f32x4 acc[FM][FN];
    #pragma unroll
    for (int m = 0; m < FM; m++)
        #pragma unroll
        for (int n = 0; n < FN; n++) acc[m][n] = f32x4{0.f, 0.f, 0.f, 0.f};

    const bf16* Abase = A  + (size_t)bm * BM * K;
    const bf16* Bbase = BT + (size_t)bn * BN * K;
    const int Ts = (K >> 6) / KSPLIT;
    const int t0 = ks * Ts;

    const int l15 = lane & 15;
    const int swz = (((lane >> 4) ^ ((l15 >> 1) & 3)) << 3);
    const int arow0 = wr * (BM / 2) + l15;
    const int brow0 = wc * (BN / 4) + l15;

#define ABASE_(p_, ks_) (((p_)*2 + (ks_)) * ASUB)
#define BBASE_(p_, ks_) (4*ASUB + ((p_)*2 + (ks_)) * BSUB)
#define STAGE_A(p_, kt_, ks_) { _Pragma("unroll") for (int i = 0; i < LA; i++) { \
    const int c = tid + i * 512; \
    if ((ACH & 511) == 0 || c < ACH) { \
      const int rw = c >> 2; \
      const int kc = (c & 3) ^ ((rw >> 1) & 3); \
      async_copy16(Abase + (size_t)rw * K + (kt_)*64 + (ks_)*32 + kc*8, \
                   &smem[ABASE_(p_, ks_) + c*8]); } } }
#define STAGE_B(p_, kt_, ks_) { _Pragma("unroll") for (int i = 0; i < LB; i++) { \
    const int c = tid + i * 512; \
    if ((BCH & 511) == 0 || c < BCH) { \
      const int rw = c >> 2; \
      const int kc = (c & 3) ^ ((rw >> 1) & 3); \
      async_copy16(Bbase + (size_t)rw * K + (kt_)*64 + (ks_)*32 + kc*8, \
                   &smem[BBASE_(p_, ks_) + c*8]); } } }
#define LOAD_B(p_, ks_) { _Pragma("unroll") for (int n = 0; n < FN; n++) \
    bfv[n] = *(const bf16x8*)&smem[BBASE_(p_, ks_) + (brow0 + n*16)*32 + swz]; }
#define LOAD_A(p_, ks_, mg) { _Pragma("unroll") for (int m = 0; m < HM; m++) \
    af[m] = *(const bf16x8*)&smem[ABASE_(p_, ks_) + (arow0 + ((mg)*HM + m)*16)*32 + swz]; }
#define QUAD(mg) { __builtin_amdgcn_s_setprio(1); \
    _Pragma("unroll") for (int m = 0; m < HM; m++) \
      _Pragma("unroll") for (int n = 0; n < FN; n++) \
        acc[(mg)*HM + m][n] = mfma16(af[m], bfv[n], acc[(mg)*HM + m][n]); \
    __builtin_amdgcn_s_setprio(0); }

    STAGE_A(0, t0, 0); STAGE_B(0, t0, 0); STAGE_A(0, t0, 1); STAGE_B(0, t0, 1);
    wait_g(wcount);
    __builtin_amdgcn_s_barrier();

    for (int tl = 0; tl < Ts; tl++) {
        const int b = tl & 1;
        const int kt1 = t0 + tl + 1;
        const bool more = (tl + 1) < Ts;
        bf16x8 af[HM], bfv[FN];
        LOAD_B(b, 0); LOAD_A(b, 0, 0);
        if (more) STAGE_A(b ^ 1, kt1, 0);
        __builtin_amdgcn_s_barrier();
        QUAD(0);
        __builtin_amdgcn_s_barrier();
        LOAD_A(b, 0, 1);
        if (more) STAGE_B(b ^ 1, kt1, 0);
        __builtin_amdgcn_s_barrier();
        QUAD(1);
        if (more) wait_g(wcount); else waitv<0>();
        __builtin_amdgcn_s_barrier();
        LOAD_B(b, 1); LOAD_A(b, 1, 0);
        if (more) STAGE_A(b ^ 1, kt1, 1);
        __builtin_amdgcn_s_barrier();
        QUAD(0);
        __builtin_amdgcn_s_barrier();
        LOAD_A(b, 1, 1);
        if (more) STAGE_B(b ^ 1, kt1, 1);
        __builtin_amdgcn_s_barrier();
        QUAD(1);
        if (more) wait_g(wcount);
        __builtin_amdgcn_s_barrier();
    }

    const int er = bm * BM + wr * (BM / 2) + ((lane >> 4) << 2);
    const int ec = bn * BN + wc * (BN / 4) + l15;
    #pragma unroll
    for (int n = 0; n < FN; n++) {
        const int col = ec + n * 16;
        const float bv = (EPI == 3) ? 0.f : ((KSPLIT > 1 && ks != 0) ? 0.f : bias[col]);
        #pragma unroll
        for (int m = 0; m < FM; m++) {
            const int row0 = er + m * 16;
            if constexpr (EPI == 4) {
                if (col < 2048) {
                    #pragma unroll
                    for (int i = 0; i < 4; i++)
                        outb[(size_t)(row0 + i) * N + col] = (bf16)(acc[m][n][i] + bv);
                } else {
                    bf16x4 o4;
                    #pragma unroll
                    for (int i = 0; i < 4; i++) o4[i] = (bf16)(acc[m][n][i] + bv);
                    const int b_ = row0 >> 10, tok = row0 & 1023;
                    *(bf16x4*)&vt[((size_t)(b_ * 1024 + (col - 2048))) * 1024 + tok] = o4;
                }
            } else {
                #pragma unroll
                for (int i = 0; i < 4; i++) {
                    const float v = acc[m][n][i] + bv;
                    const size_t off = (size_t)(row0 + i) * N + col;
                    if constexpr (EPI == 0) outb[off] = (bf16)v;
                    else if constexpr (EPI == 1) {
                        if constexpr (KSPLIT > 1) atomicAdd(&resid[off], v);
                        else resid[off] += v;
                    }
                    else if constexpr (EPI == 2) {
                        outb[off] = (bf16)(0.5f * v * (1.f + erff(v * 0.70710678118f)));
                    } else {
                        outf[off] = v;
                    }
                }
            }
        }
    }
#undef ABASE_
#undef BBASE_
#undef STAGE_A
#undef STAGE_B
#undef LOAD_A
#undef LOAD_B
#undef QUAD
}

// ---------------- orchestration ----------------
extern "C" void kernel_launch(void* const* d_in, const int* in_sizes, int n_in,
                              void* d_out, int out_size, void* d_ws, size_t ws_size,
                              hipStream_t stream)
{
    const int*   ids     = (const int*)  d_in[0];
    const float* tok_emb = (const float*)d_in[1];
    const float* pos_emb = (const float*)d_in[2];
    const float* ln1_s   = (const float*)d_in[3];
    const float* ln1_b   = (const float*)d_in[4];
    const float* qkv_w   = (const float*)d_in[5];
    const float* qkv_b   = (const float*)d_in[6];
    const float* out_w   = (const float*)d_in[7];
    const float* out_b   = (const float*)d_in[8];
    const float* ln2_s   = (const float*)d_in[9];
    const float* ln2_b   = (const float*)d_in[10];
    const float* w1      = (const float*)d_in[11];
    const float* b1      = (const float*)d_in[12];
    const float* w2      = (const float*)d_in[13];
    const float* b2      = (const float*)d_in[14];
    const float* lnf_s   = (const float*)d_in[15];
    const float* lnf_b   = (const float*)d_in[16];
    const float* lm_w    = (const float*)d_in[17];

    char* ws = (char*)d_ws;
    float* x    = (float*)ws;  ws += (size_t)2048 * 1024 * 4;
    bf16*  h    = (bf16*)ws;   ws += (size_t)2048 * 1024 * 2;
    bf16*  qkvb = (bf16*)ws;   ws += (size_t)2048 * 3072 * 2;
    bf16*  attno= (bf16*)ws;   ws += (size_t)2048 * 1024 * 2;
    bf16*  vT   = (bf16*)ws;   ws += (size_t)32 * 64 * 1024 * 2;
    bf16*  ff   = (bf16*)ws;   ws += (size_t)2048 * 4096 * 2;
    bf16*  wTq2 = (bf16*)ws;   ws += (size_t)2 * 3072 * 1024 * 2;   // double-buffered
    bf16*  wTo_all = (bf16*)ws; ws += (size_t)6 * 1024 * 1024 * 2;
    bf16*  wT1  = (bf16*)ws;   ws += (size_t)4096 * 1024 * 2;
    bf16*  wT2  = (bf16*)ws;   ws += (size_t)1024 * 4096 * 2;
    bf16*  wTlm = (bf16*)ws;   ws += (size_t)32000 * 1024 * 2;

    for (int l = 0; l < 6; l++) {
        bf16* wTq_cur = wTq2 + (size_t)(l & 1) * 3072 * 1024;
        bf16* wTq_nxt = wTq2 + (size_t)((l + 1) & 1) * 3072 * 1024;
        if (l == 0) {
            front_kernel<<<2816, 256, 0, stream>>>(
                ids, tok_emb, pos_emb, x, ln1_s, ln1_b, h, qkv_w, wTq_cur);
        } else {
            ln_kernel<<<2048, 256, 0, stream>>>(x, ln1_s + l*1024, ln1_b + l*1024, h);
        }
        gemm256_kernel<128,192,4,1><<<256, 512, 81920, stream>>>(
            h, wTq_cur, qkv_b + l*3072, nullptr, qkvb, nullptr, vT, 3072, 1024);
        const int nbq = (l < 5) ? 768 : 0;
        const int lm_lo = (8000 * l) / 6;
        const int lm_cnt = (8000 * (l + 1)) / 6 - lm_lo;
        attn_wcvt_kernel<<<512 + nbq + 1024 + 1024 + 256 + lm_cnt, 256, 0, stream>>>(
            qkvb, vT, attno,
            (l < 5) ? qkv_w + (size_t)(l+1)*1024*3072 : nullptr, wTq_nxt, nbq,
            w1 + (size_t)l*1024*4096, wT1,
            w2 + (size_t)l*4096*1024, wT2,
            out_w + (size_t)l*1024*1024, wTo_all + (size_t)l*1024*1024,
            lm_w, wTlm, lm_lo);
        // out-proj: BN=128, KSPLIT=2 -> 256 blocks, 64KB LDS (2/CU), Ts=8, atomics halved
        gemm256_kernel<128,128,1,2><<<256, 512, 65536, stream>>>(
            attno, wTo_all + (size_t)l*1024*1024, out_b + l*1024, x, nullptr, nullptr, nullptr, 1024, 1024);
        ln_kernel<<<2048, 256, 0, stream>>>(x, ln2_s + l*1024, ln2_b + l*1024, h);
        gemm256_kernel<128,256,2,1><<<256, 512, 98304, stream>>>(
            h, wT1, b1 + l*4096, nullptr, ff, nullptr, nullptr, 4096, 1024);
        // mlp2: BN=128, KSPLIT=2 -> 256 blocks, 64KB LDS (2/CU), Ts=32, atomics halved
        gemm256_kernel<128,128,1,2><<<256, 512, 65536, stream>>>(
            ff, wT2, b2 + l*1024, x, nullptr, nullptr, nullptr, 1024, 4096);
    }
    ln_kernel<<<2048, 256, 0, stream>>>(x, lnf_s, lnf_b, h);
    gemm256_kernel<256,256,3,1><<<8*125, 512, 131072, stream>>>(
        h, wTlm, nullptr, nullptr, nullptr, (float*)d_out, nullptr, 32000, 1024);
}